// Round 15
// baseline (34.010 us; speedup 1.0000x reference)
//
#include <hip/hip_runtime.h>

// GaussianAntecedent: out[n,r] = mem[n,r] / (sum_r mem[n,r] + 1e-8)
// mem = exp2( sum_d -clamp(q*x+pn, +-K)^2 ),  K = sqrt(-log2(1e-8))
//   q = sqrt(0.5*log2 e)/(sigma+eps), pn = -c*q
//   (clamped t^2 == -L exactly when saturated => identical to max(-t^2,L))
//
// R14 post-mortem: basin = distributed per-wave overhead. R15 cuts:
//  1) memL (33KB LDS round-trip) KILLED: mem stays in 32 regs; each
//     lane's 16 rules are contiguous in the row -> direct float4 quad
//     stores (4 per row per lane); -1 barrier, -100k ds_writes.
//  2) med3 clamp: t_c = fminf(fmaxf(t,-K),K) fuses to v_med3_f32;
//     acc = pk_fma(t_c,-t_c,acc). 5 -> 4 VALU slots per 2 elems.
//  3) LDS 52.7 -> 18.5KB: occupancy VGPR-bound at 4 waves/SIMD (was 3).

typedef float v2f __attribute__((ext_vector_type(2)));

constexpr int DDIM = 32;
constexpr int RR   = 64;
constexpr int ROWS = 128;   // rows per block (2 per lane)
constexpr int PP   = 5;     // partials pitch (floats)

__device__ inline float fast_exp2(float x) {
#if __has_builtin(__builtin_amdgcn_exp2f)
    return __builtin_amdgcn_exp2f(x);
#else
    return exp2f(x);
#endif
}

__global__ __launch_bounds__(256, 4) void gauss_main(
    const float* __restrict__ X,
    const float* __restrict__ centers,
    const float* __restrict__ sigma,
    float* __restrict__ out, int N)
{
    __shared__ float tabL[RR * 64];       // 16 KB  [rule]{q[32]|pn[32]}
    __shared__ float partL[ROWS * PP];    // 2.5 KB [row][wave]

    const int tid  = threadIdx.x;
    const int lane = tid & 63;
    const int w    = tid >> 6;
    const int n0   = blockIdx.x * ROWS;

    // ---- own rows -> VGPRs (issued first; latency hides table build) ----
    const int na = n0 + lane;
    const int nb = n0 + 64 + lane;
    const int ca = (na < N) ? na : (N - 1);
    const int cb = (nb < N) ? nb : (N - 1);
    const float4* __restrict__ xra =
        reinterpret_cast<const float4*>(X + (size_t)ca * DDIM);
    const float4* __restrict__ xrb =
        reinterpret_cast<const float4*>(X + (size_t)cb * DDIM);
    v2f xa2[16], xb2[16];
    #pragma unroll
    for (int j = 0; j < 8; ++j) {
        float4 va = xra[j], vb = xrb[j];
        xa2[2 * j]     = (v2f){va.x, va.y};
        xa2[2 * j + 1] = (v2f){va.z, va.w};
        xb2[2 * j]     = (v2f){vb.x, vb.y};
        xb2[2 * j + 1] = (v2f){vb.z, vb.w};
    }

    // ---- build q/pn table in LDS (once per block; 8 divides/thread) ----
    const float SQK = 0.84932180028801907f;   // sqrt(0.5 * log2(e))
    #pragma unroll
    for (int i = 0; i < 8; ++i) {
        const int pi = tid * 8 + i;           // (rule, dim) pair 0..2047
        const int r  = pi >> 5, d = pi & 31;
        float q  = SQK / (sigma[r * DDIM + d] + 1e-8f);
        tabL[r * 64 + d]        = q;
        tabL[r * 64 + DDIM + d] = -centers[r * DDIM + d] * q;
    }

    #pragma unroll
    for (int j = 0; j < 16; ++j) asm volatile("" : "+v"(xa2[j]), "+v"(xb2[j]));

    __syncthreads();   // table ready

    const float K = 5.1551357f;   // sqrt(26.575424759098897) = sqrt(-log2 1e-8)
    float mema[16], memb[16];

    // ---- 16 rules for this wave; both rows per constant read ----
    #pragma unroll
    for (int rr = 0; rr < 16; ++rr) {
        const int r = w * 16 + rr;
        const float4* __restrict__ tp =
            reinterpret_cast<const float4*>(&tabL[r * 64]);

        v2f Aa[2] = {{0.f,0.f},{0.f,0.f}};
        v2f Ab[2] = {{0.f,0.f},{0.f,0.f}};
        #pragma unroll
        for (int j = 0; j < 8; ++j) {
            float4 qf = tp[j];        // q  dims 4j..4j+3 (uniform broadcast)
            float4 pf = tp[8 + j];    // pn dims 4j..4j+3
            v2f q0 = {qf.x, qf.y}, q1 = {qf.z, qf.w};
            v2f p0 = {pf.x, pf.y}, p1 = {pf.z, pf.w};
            v2f ta0 = __builtin_elementwise_fma(q0, xa2[2*j],   p0);
            v2f ta1 = __builtin_elementwise_fma(q1, xa2[2*j+1], p1);
            v2f tb0 = __builtin_elementwise_fma(q0, xb2[2*j],   p0);
            v2f tb1 = __builtin_elementwise_fma(q1, xb2[2*j+1], p1);
            // clamp to [-K, K]: fminf(fmaxf(.)) fuses to v_med3_f32
            ta0.x = fminf(fmaxf(ta0.x, -K), K); ta0.y = fminf(fmaxf(ta0.y, -K), K);
            ta1.x = fminf(fmaxf(ta1.x, -K), K); ta1.y = fminf(fmaxf(ta1.y, -K), K);
            tb0.x = fminf(fmaxf(tb0.x, -K), K); tb0.y = fminf(fmaxf(tb0.y, -K), K);
            tb1.x = fminf(fmaxf(tb1.x, -K), K); tb1.y = fminf(fmaxf(tb1.y, -K), K);
            Aa[0] = __builtin_elementwise_fma(ta0, -ta0, Aa[0]);
            Aa[1] = __builtin_elementwise_fma(ta1, -ta1, Aa[1]);
            Ab[0] = __builtin_elementwise_fma(tb0, -tb0, Ab[0]);
            Ab[1] = __builtin_elementwise_fma(tb1, -tb1, Ab[1]);
        }
        v2f aa = Aa[0] + Aa[1];
        v2f ab = Ab[0] + Ab[1];
        mema[rr] = fast_exp2(aa.x + aa.y);
        memb[rr] = fast_exp2(ab.x + ab.y);
    }

    // per-lane partial sums over this wave's 16 rules (tree)
    float Sa = 0.f, Sb = 0.f;
    #pragma unroll
    for (int rr = 0; rr < 16; ++rr) { Sa += mema[rr]; Sb += memb[rr]; }
    partL[lane * PP + w]        = Sa;   // (5*lane+w)%32: conflict-free
    partL[(64 + lane) * PP + w] = Sb;

    __syncthreads();   // partials ready

    float sa = partL[lane * PP + 0] + partL[lane * PP + 1] +
               partL[lane * PP + 2] + partL[lane * PP + 3];
    float sb = partL[(64+lane) * PP + 0] + partL[(64+lane) * PP + 1] +
               partL[(64+lane) * PP + 2] + partL[(64+lane) * PP + 3];
    float rsa = __builtin_amdgcn_rcpf(sa + 1e-8f);
    float rsb = __builtin_amdgcn_rcpf(sb + 1e-8f);

    // ---- direct stores: each lane owns 64B (16 rules) of its rows ----
    if (na < N) {
        float* op = out + (size_t)na * RR + w * 16;
        #pragma unroll
        for (int q = 0; q < 4; ++q) {
            float4 o;
            o.x = mema[4*q+0] * rsa; o.y = mema[4*q+1] * rsa;
            o.z = mema[4*q+2] * rsa; o.w = mema[4*q+3] * rsa;
            *reinterpret_cast<float4*>(op + 4 * q) = o;
        }
    }
    if (nb < N) {
        float* op = out + (size_t)nb * RR + w * 16;
        #pragma unroll
        for (int q = 0; q < 4; ++q) {
            float4 o;
            o.x = memb[4*q+0] * rsb; o.y = memb[4*q+1] * rsb;
            o.z = memb[4*q+2] * rsb; o.w = memb[4*q+3] * rsb;
            *reinterpret_cast<float4*>(op + 4 * q) = o;
        }
    }
}

extern "C" void kernel_launch(void* const* d_in, const int* in_sizes, int n_in,
                              void* d_out, int out_size, void* d_ws, size_t ws_size,
                              hipStream_t stream) {
    const float* X       = (const float*)d_in[0];
    const float* centers = (const float*)d_in[1];
    const float* sigma   = (const float*)d_in[2];
    float* out = (float*)d_out;

    const int N = in_sizes[0] / DDIM;  // 100000
    const int grid = (N + ROWS - 1) / ROWS;   // 782
    gauss_main<<<grid, 256, 0, stream>>>(X, centers, sigma, out, N);
}

// Round 16
// 29.958 us; speedup vs baseline: 1.1353x; 1.1353x over previous
//
#include <hip/hip_runtime.h>

// GaussianAntecedent: out[n,r] = mem[n,r] / (sum_r mem[n,r] + 1e-8)
// mem = exp2( sum_d -clamp(q*x+pn, +-K)^2 ),  K = sqrt(-log2(1e-8))
//   q = sqrt(0.5*log2 e)/(sigma+eps), pn = -c*q
//
// R15 post-mortem: direct strided stores lost to R14's LDS-transpose
// (34.0 vs 32.9) -> keep R14 structure. med3 clamp numerics validated in
// R15 (absmax identical). R16 = R14 + med3 inner loop ONLY (single var):
// per j: 4 v2f-fma + 8 med3 + 4 v2f-fma (24 scalar slots if v2f ops
// scalarize, vs R14's 32). Diagnostic: a ~3us win => VALU count is the
// lever (v2f scalarized); no change => pk ops are real, attack transport.

typedef float v2f __attribute__((ext_vector_type(2)));

constexpr int DDIM = 32;
constexpr int RR   = 64;
constexpr int ROWS = 128;         // rows per block (2 per lane)
constexpr int MP   = 130;         // mem tile pitch (floats)
constexpr int PP   = 5;           // partials pitch

__device__ inline float fast_exp2(float x) {
#if __has_builtin(__builtin_amdgcn_exp2f)
    return __builtin_amdgcn_exp2f(x);
#else
    return exp2f(x);
#endif
}

__global__ __launch_bounds__(256, 2) void gauss_main(
    const float* __restrict__ X,
    const float* __restrict__ centers,
    const float* __restrict__ sigma,
    float* __restrict__ out, int N)
{
    __shared__ float tabL[RR * 64];       // 16 KB  [rule]{q[32]|pn[32]}
    __shared__ float memL[RR * MP];       // 33.3 KB [rule][row]
    __shared__ float partL[ROWS * PP];    // 2.56 KB [row][wave]
    __shared__ float rsL[ROWS];           // 0.5 KB  rcp(S) per row

    const int tid  = threadIdx.x;
    const int lane = tid & 63;
    const int w    = tid >> 6;
    const int n0   = blockIdx.x * ROWS;

    // ---- own rows -> VGPRs (issued first; latency hides table build) ----
    const int na = n0 + lane;
    const int nb = n0 + 64 + lane;
    const int ca = (na < N) ? na : (N - 1);
    const int cb = (nb < N) ? nb : (N - 1);
    const float4* __restrict__ xra =
        reinterpret_cast<const float4*>(X + (size_t)ca * DDIM);
    const float4* __restrict__ xrb =
        reinterpret_cast<const float4*>(X + (size_t)cb * DDIM);
    v2f xa2[16], xb2[16];
    #pragma unroll
    for (int j = 0; j < 8; ++j) {
        float4 va = xra[j], vb = xrb[j];
        xa2[2 * j]     = (v2f){va.x, va.y};
        xa2[2 * j + 1] = (v2f){va.z, va.w};
        xb2[2 * j]     = (v2f){vb.x, vb.y};
        xb2[2 * j + 1] = (v2f){vb.z, vb.w};
    }

    // ---- build q/pn table in LDS (once per block; 8 divides/thread) ----
    const float SQK = 0.84932180028801907f;   // sqrt(0.5 * log2(e))
    #pragma unroll
    for (int i = 0; i < 8; ++i) {
        const int pi = tid * 8 + i;           // (rule, dim) pair 0..2047
        const int r  = pi >> 5, d = pi & 31;
        float q  = SQK / (sigma[r * DDIM + d] + 1e-8f);
        tabL[r * 64 + d]        = q;
        tabL[r * 64 + DDIM + d] = -centers[r * DDIM + d] * q;
    }

    #pragma unroll
    for (int j = 0; j < 16; ++j) asm volatile("" : "+v"(xa2[j]), "+v"(xb2[j]));

    __syncthreads();   // table ready

    const float K = 5.1551357f;   // sqrt(26.575424759098897) = sqrt(-log2 1e-8)
    const float LC = -26.575424759098897f;
    (void)LC;
    float Sa = 0.f, Sb = 0.f;

    // ---- 16 rules for this wave; both rows per constant read ----
    #pragma unroll
    for (int rr = 0; rr < 16; ++rr) {
        const int r = w * 16 + rr;
        const float4* __restrict__ tp =
            reinterpret_cast<const float4*>(&tabL[r * 64]);

        v2f Aa[2] = {{0.f,0.f},{0.f,0.f}};
        v2f Ab[2] = {{0.f,0.f},{0.f,0.f}};
        #pragma unroll
        for (int j = 0; j < 8; ++j) {
            float4 qf = tp[j];        // q  dims 4j..4j+3 (uniform broadcast)
            float4 pf = tp[8 + j];    // pn dims 4j..4j+3
            v2f q0 = {qf.x, qf.y}, q1 = {qf.z, qf.w};
            v2f p0 = {pf.x, pf.y}, p1 = {pf.z, pf.w};
            v2f ta0 = __builtin_elementwise_fma(q0, xa2[2*j],   p0);
            v2f ta1 = __builtin_elementwise_fma(q1, xa2[2*j+1], p1);
            v2f tb0 = __builtin_elementwise_fma(q0, xb2[2*j],   p0);
            v2f tb1 = __builtin_elementwise_fma(q1, xb2[2*j+1], p1);
            // clamp to [-K, K]: fminf(fmaxf(.)) fuses to v_med3_f32
            ta0.x = fminf(fmaxf(ta0.x, -K), K); ta0.y = fminf(fmaxf(ta0.y, -K), K);
            ta1.x = fminf(fmaxf(ta1.x, -K), K); ta1.y = fminf(fmaxf(ta1.y, -K), K);
            tb0.x = fminf(fmaxf(tb0.x, -K), K); tb0.y = fminf(fmaxf(tb0.y, -K), K);
            tb1.x = fminf(fmaxf(tb1.x, -K), K); tb1.y = fminf(fmaxf(tb1.y, -K), K);
            Aa[0] = __builtin_elementwise_fma(ta0, -ta0, Aa[0]);
            Aa[1] = __builtin_elementwise_fma(ta1, -ta1, Aa[1]);
            Ab[0] = __builtin_elementwise_fma(tb0, -tb0, Ab[0]);
            Ab[1] = __builtin_elementwise_fma(tb1, -tb1, Ab[1]);
        }
        v2f aa = Aa[0] + Aa[1];
        v2f ab = Ab[0] + Ab[1];
        float ma = fast_exp2(aa.x + aa.y);
        float mb = fast_exp2(ab.x + ab.y);
        Sa += ma;
        Sb += mb;
        memL[r * MP + lane]      = ma;   // stride-1 across lanes: clean
        memL[r * MP + 64 + lane] = mb;
    }
    partL[lane * PP + w]        = Sa;    // (5*lane+w)%32: 2-way, free
    partL[(64 + lane) * PP + w] = Sb;

    __syncthreads();   // mem tile + partials ready

    if (tid < ROWS) {
        float s = partL[tid * PP + 0] + partL[tid * PP + 1] +
                  partL[tid * PP + 2] + partL[tid * PP + 3];
        rsL[tid] = __builtin_amdgcn_rcpf(s + 1e-8f);
    }
    __syncthreads();   // rs ready

    // ---- epilogue: contiguous 4KB-per-step float4 stores ----
    const int nvalid = N - n0;   // rows in this block (128 except last)
    #pragma unroll
    for (int ch = 0; ch < 8; ++ch) {
        const int f4  = ch * 256 + tid;       // 0..2047
        const int row = f4 >> 4;              // 0..127
        const int r4  = (f4 & 15) * 4;        // rule quad base
        if (row < nvalid) {
            float rs = rsL[row];
            float4 o;
            o.x = memL[(r4 + 0) * MP + row] * rs;
            o.y = memL[(r4 + 1) * MP + row] * rs;
            o.z = memL[(r4 + 2) * MP + row] * rs;
            o.w = memL[(r4 + 3) * MP + row] * rs;
            *reinterpret_cast<float4*>(&out[(size_t)(n0 + row) * RR + r4]) = o;
        }
    }
}

extern "C" void kernel_launch(void* const* d_in, const int* in_sizes, int n_in,
                              void* d_out, int out_size, void* d_ws, size_t ws_size,
                              hipStream_t stream) {
    const float* X       = (const float*)d_in[0];
    const float* centers = (const float*)d_in[1];
    const float* sigma   = (const float*)d_in[2];
    float* out = (float*)d_out;

    const int N = in_sizes[0] / DDIM;  // 100000
    const int grid = (N + ROWS - 1) / ROWS;   // 782
    gauss_main<<<grid, 256, 0, stream>>>(X, centers, sigma, out, N);
}